// Round 8
// baseline (420.439 us; speedup 1.0000x reference)
//
#include <hip/hip_runtime.h>

// ResLSTM: B=4096, T=512, H=32. One wave64 per batch element.
// Lane l computes gate rows l and l+64:
//   lanes 0..31:  row l = i,  row l+64 = g
//   lanes 32..63: row l = f,  row l+64 = o
//
// History: R4 LDS h-broadcast 407->330; R5-R7 register pinning all neutral.
// R8 pipe arithmetic: R4-R7 were DS-PIPE-BOUND, not weight-bound:
//   16 waves/CU x 8 ds_read_b128/step x 12 cyc = 1536 cyc/CU/step
//   = 98.7% of the observed 332 us. Weight L1 re-reads were only ~8%.
// R8: kill ALL LDS reads. h[j] broadcast via 32 v_readlane -> SGPR, consumed
// as the single SGPR operand of each v_fma_f32. h-pressure moves from VGPRs
// (8 live float4s) to SGPRs, giving the allocator slack to keep the 64
// weight floats resident. No LDS in the kernel at all.

static constexpr int T_LEN = 512;
static constexpr int H = 32;

__device__ __forceinline__ float rl_c(float v, int l) {
    return __int_as_float(__builtin_amdgcn_readlane(__float_as_int(v), l));
}

// exp2-based sigmoid: sigmoid(x) = rcp(1 + exp2(x * -log2(e)))
__device__ __forceinline__ float sig_e2(float x_times_nlog2e) {
    return __builtin_amdgcn_rcpf(1.0f + __builtin_amdgcn_exp2f(x_times_nlog2e));
}

__global__ void
__attribute__((amdgpu_flat_work_group_size(256, 256), amdgpu_waves_per_eu(4, 4)))
reslstm_kernel(const float* __restrict__ x,
               const float* __restrict__ W_ih,
               const float* __restrict__ W_hh,
               const float* __restrict__ b_ih,
               const float* __restrict__ b_hh,
               const float* __restrict__ W_fc,
               const float* __restrict__ b_fc,
               float* __restrict__ out, int B)
{
    const int lane = threadIdx.x & 63;
    const int wv   = threadIdx.x >> 6;
    const int b    = (blockIdx.x << 2) + wv;
    if (b >= B) return;                       // wave-uniform guard

    const int r0 = lane;                      // i | f
    const int r1 = lane + 64;                 // g | o

    // W_hh rows for this lane -> 16 float4 = 64 VGPRs.
    const float4* pa = reinterpret_cast<const float4*>(W_hh + r0 * H);
    const float4* pb = reinterpret_cast<const float4*>(W_hh + r1 * H);
    const float4 a0 = pa[0], a1 = pa[1], a2 = pa[2], a3 = pa[3],
                 a4 = pa[4], a5 = pa[5], a6 = pa[6], a7 = pa[7];
    const float4 q0 = pb[0], q1 = pb[1], q2 = pb[2], q3 = pb[3],
                 q4 = pb[4], q5 = pb[5], q6 = pb[6], q7 = pb[7];

    const float wih0  = W_ih[r0];
    const float wih1  = W_ih[r1];
    const float bias0 = b_ih[r0] + b_hh[r0];
    const float bias1 = b_ih[r1] + b_hh[r1];

    // Branchless tanh-vs-sigmoid for the r1 gate: tanh(x)=2*sigmoid(2x)-1.
    const bool  lo = (lane < 32);
    constexpr float NL2E = -1.4426950408889634f;
    const float e1 = lo ? 2.0f * NL2E : NL2E;
    const float s1 = lo ? 2.0f : 1.0f;
    const float t1 = lo ? -1.0f : 0.0f;

    float h = 0.0f, c = 0.0f;
    const float* xrow = x + (size_t)b * T_LEN;

// Broadcast h[K]/h[K+1] via readlane (exact, no LDS); feed 4 FMAs each,
// alternating accumulator pairs for ILP.
#define MAC2(va, vq, cA, cB, K)                                           \
    {                                                                     \
        const float hk = rl_c(h, (K));                                    \
        cA = __builtin_fmaf(va, hk, cA);                                  \
        cB = __builtin_fmaf(vq, hk, cB);                                  \
    }
#define MAC8(v4a, v4q, K)                                                 \
    MAC2(v4a.x, v4q.x, aA,  aB,  (K) + 0)                                 \
    MAC2(v4a.y, v4q.y, aA2, aB2, (K) + 1)                                 \
    MAC2(v4a.z, v4q.z, aA,  aB,  (K) + 2)                                 \
    MAC2(v4a.w, v4q.w, aA2, aB2, (K) + 3)

    for (int tc = 0; tc < T_LEN / 64; ++tc) {
        const float xv = xrow[(tc << 6) + lane];   // coalesced 64-float chunk
        #pragma unroll 4
        for (int tt = 0; tt < 64; ++tt) {
            const float xt = rl_c(xv, tt);         // x[b][t], wave-uniform
            float aA  = __builtin_fmaf(xt, wih0, bias0);
            float aB  = __builtin_fmaf(xt, wih1, bias1);
            float aA2 = 0.0f, aB2 = 0.0f;
            MAC8(a0, q0, 0)  MAC8(a1, q1, 4)
            MAC8(a2, q2, 8)  MAC8(a3, q3, 12)
            MAC8(a4, q4, 16) MAC8(a5, q5, 20)
            MAC8(a6, q6, 24) MAC8(a7, q7, 28)
            aA += aA2; aB += aB2;
            const float g0 = sig_e2(aA * NL2E);                       // i | f
            const float g1 = __builtin_fmaf(s1, sig_e2(aB * e1), t1); // g | o
            const float fo = __shfl_xor(g0, 32);   // lanes<32 get f[j]
            const float og = __shfl_xor(g1, 32);   // lanes<32 get o[j]
            // lanes>=32 carry bounded garbage c,h, never read (readlane
            // broadcasts touch lanes 0..31 only; values stay finite:
            // c_up = i*c_up + f*o is a contraction).
            c = __builtin_fmaf(fo, c, g0 * g1);                       // f*c+i*g
            const float th = __builtin_fmaf(2.0f, sig_e2(c * (2.0f * NL2E)), -1.0f);
            h = og * th;                                              // o*tanh(c)
        }
    }
#undef MAC8
#undef MAC2

    // out[b] = sum_j h[j]*W_fc[j] + b_fc  (butterfly reduce over the wave)
    float val = lo ? h * W_fc[lane & (H - 1)] : 0.0f;
    #pragma unroll
    for (int off = 32; off >= 1; off >>= 1)
        val += __shfl_xor(val, off);
    if (lane == 0) out[b] = val + b_fc[0];
}

extern "C" void kernel_launch(void* const* d_in, const int* in_sizes, int n_in,
                              void* d_out, int out_size, void* d_ws, size_t ws_size,
                              hipStream_t stream) {
    const float* x    = (const float*)d_in[0];
    const float* W_ih = (const float*)d_in[1];
    const float* W_hh = (const float*)d_in[2];
    const float* b_ih = (const float*)d_in[3];
    const float* b_hh = (const float*)d_in[4];
    const float* W_fc = (const float*)d_in[5];
    const float* b_fc = (const float*)d_in[6];
    float* out = (float*)d_out;
    const int B = in_sizes[0] / T_LEN;        // 4096
    dim3 block(256);                          // 4 waves = 4 batch elements
    dim3 grid((B + 3) / 4);                   // 1024 blocks -> 4 waves/SIMD
    reslstm_kernel<<<grid, block, 0, stream>>>(x, W_ih, W_hh, b_ih, b_hh,
                                               W_fc, b_fc, out, B);
}